// Round 10
// baseline (357.967 us; speedup 1.0000x reference)
//
#include <hip/hip_runtime.h>
#include <stdint.h>

// GMNConv R10 = R9 + atomic-free scatter (rank recorded during hist, 8-way
// sub-counter spread per node to cut atomic line contention / XCD ping-pong).
//  pre_k    : weight prep + x cast (+U x-cols) + hist (deg8, rnk)
//  scan_k   : offs + per-bucket bases sb8 + degt
//  mid_k    : PQ GEMM || scatter (no atomics) || transpose x
//  gather_k : S[n] = sum relu(P[src]+Q[n])
//  msgattn_k: msg GEMM || block-diag cross-attention
//  h1/h2/out: update MLP GEMMs

typedef unsigned short u16;
typedef __bf16 bf16x8 __attribute__((ext_vector_type(8)));
typedef float f32x4 __attribute__((ext_vector_type(4)));

#define NN 8192
#define DD 128
#define EE 131072
#define GS 128

__device__ __forceinline__ float bf2f(u16 u){
  return __uint_as_float(((uint32_t)u) << 16);
}
__device__ __forceinline__ u16 f2bf(float f){
  uint32_t x = __float_as_uint(f);
  return (u16)((x + 0x7fffu + ((x >> 16) & 1u)) >> 16);
}
__device__ __forceinline__ void gload16(const u16* g, u16* l){
  __builtin_amdgcn_global_load_lds(
      (const __attribute__((address_space(1))) uint32_t*)(uintptr_t)g,
      (__attribute__((address_space(3))) uint32_t*)(uintptr_t)l, 16, 0, 0);
}

struct GArgs {
  const float *x1, *x2;
  const int   *ei1, *ei2;
  const float *mW1, *mb1, *mW2, *mb2;
  const float *uW1, *ub1, *uW2, *ub2, *uW3, *ub3;
  float* out;
  u16 *S, *PQ, *xb, *xt, *U, *H1, *H2;
  int *deg8, *degt, *sb8, *rnk;     // deg8/sb8: [2][NN*8]; degt: [2][NN]; rnk: [2][EE]
  int *offs1, *offs2, *srt1, *srt2;
  u16 *WtPQ; float* bPQ;
  u16 *Wtm2, *Wtu1, *Wtu2, *Wtu3;
};

// ---- GEMM body, BK=128 staged as 4 panels of m97 geometry ----
template<bool RELU, bool DEGBIAS, bool RES, typename OT>
__device__ __forceinline__ void gemm_body(
    const u16* __restrict__ A, int lda,
    const u16* __restrict__ Wt, const float* __restrict__ bias,
    const int* __restrict__ deg,
    const float* __restrict__ res1, const float* __restrict__ res2,
    OT* __restrict__ out, int ldc, int K, int bx, int by,
    u16* As, u16* Bs, int t)
{
  const int brow = by << 7, bcol = bx << 7;
  const int w = t >> 6, lane = t & 63;
  const int rb = (w >> 1) << 6, cb = (w & 1) << 6;
  const int lr = lane & 15, lq = lane >> 4;

  f32x4 acc[4][4];
  #pragma unroll
  for (int i = 0; i < 4; i++)
    #pragma unroll
    for (int j = 0; j < 4; j++) acc[i][j] = (f32x4){0.f, 0.f, 0.f, 0.f};

  int srow[8], scol[8];
  #pragma unroll
  for (int i = 0; i < 8; i++){
    int s = i * 256 + t;
    srow[i] = (s >> 2) & 127;
    scol[i] = ((s >> 9) << 5) + ((s & 3) << 3);
  }

  for (int kb = 0; kb < K; kb += 128){
    #pragma unroll
    for (int i = 0; i < 8; i++){
      int s = i * 256 + t;
      gload16(A  + (size_t)(brow + srow[i]) * lda + kb + scol[i], As + s * 8);
      gload16(Wt + (size_t)(bcol + srow[i]) * K   + kb + scol[i], Bs + s * 8);
    }
    __syncthreads();
    #pragma unroll
    for (int kk = 0; kk < 4; kk++){
      const u16* Ap = As + kk * 4096;
      const u16* Bp = Bs + kk * 4096;
      bf16x8 af[4], bfr[4];
      #pragma unroll
      for (int mi = 0; mi < 4; mi++)
        af[mi] = *(const bf16x8*)&Ap[(rb + mi * 16 + lr) * 32 + (lq << 3)];
      #pragma unroll
      for (int ni = 0; ni < 4; ni++)
        bfr[ni] = *(const bf16x8*)&Bp[(cb + ni * 16 + lr) * 32 + (lq << 3)];
      #pragma unroll
      for (int mi = 0; mi < 4; mi++)
        #pragma unroll
        for (int ni = 0; ni < 4; ni++)
          acc[mi][ni] = __builtin_amdgcn_mfma_f32_16x16x32_bf16(af[mi], bfr[ni], acc[mi][ni], 0, 0, 0);
    }
    __syncthreads();
  }

  #pragma unroll
  for (int mi = 0; mi < 4; mi++)
    #pragma unroll
    for (int ni = 0; ni < 4; ni++)
      #pragma unroll
      for (int rr = 0; rr < 4; rr++){
        int grow = brow + rb + mi * 16 + lq * 4 + rr;
        int gcol = bcol + cb + ni * 16 + lr;
        float v = acc[mi][ni][rr];
        if (bias) v += DEGBIAS ? (float)deg[grow] * bias[gcol] : bias[gcol];
        if constexpr (RELU) v = fmaxf(v, 0.f);
        if constexpr (RES){
          const float* rp = (grow < NN) ? res1 : res2;
          v += rp[(size_t)(grow & (NN - 1)) * ldc + gcol];
        }
        if constexpr (sizeof(OT) == 2) out[(size_t)grow * ldc + gcol] = (OT)f2bf(v);
        else                           out[(size_t)grow * ldc + gcol] = (OT)v;
      }
}

// ---- phase bodies ----
__device__ __forceinline__ void prep_weights(const GArgs& p, int vb, int t){
  if (vb < 512){                       // WtPQ [1024][128]
    int idx = vb * 256 + t; int c = idx >> 7, k = idx & 127;
    int row = (c < 512) ? k : 128 + k;
    p.WtPQ[idx] = f2bf(p.mW1[(size_t)row * 512 + (c & 511)]);
  } else if (vb < 1024){               // Wtm2 [256][512]
    int idx = (vb - 512) * 256 + t; int c = idx >> 9, k = idx & 511;
    p.Wtm2[idx] = f2bf(p.mW2[(size_t)k * 256 + c]);
  } else if (vb < 2048){               // Wtu1 [512][512]
    int idx = (vb - 1024) * 256 + t; int c = idx >> 9, k = idx & 511;
    p.Wtu1[idx] = f2bf(p.uW1[(size_t)k * 512 + c]);
  } else if (vb < 2560){               // Wtu2 [256][512]
    int idx = (vb - 2048) * 256 + t; int c = idx >> 9, k = idx & 511;
    p.Wtu2[idx] = f2bf(p.uW2[(size_t)k * 256 + c]);
  } else if (vb < 2688){               // Wtu3 [128][256]
    int idx = (vb - 2560) * 256 + t; int c = idx >> 8, k = idx & 255;
    p.Wtu3[idx] = f2bf(p.uW3[(size_t)k * 128 + c]);
  } else {                             // bPQ [1024]
    int idx = (vb - 2688) * 256 + t;
    p.bPQ[idx] = (idx < 512) ? 0.f : p.mb1[idx - 512];
  }
}

__device__ __forceinline__ void cast_x_one(const GArgs& p, int a, int t){
  int side = a >> 12, blk = a & 4095;
  const float* x = side ? p.x2 : p.x1;
  int idx = blk * 256 + t;
  int n = idx >> 7, d = idx & 127;
  u16 v = f2bf(x[idx]);
  p.xb[(size_t)side * NN * DD + idx] = v;
  p.U[((size_t)side * NN + n) * 512 + 384 + d] = v;
}

// hist: 8-way sub-counters per node + per-edge rank (enables atomic-free scatter)
__device__ __forceinline__ void hist_one(const GArgs& p, int idx, int t){
  int side = idx >> 9, blk = idx & 511, c = idx & 7;
  const int* ei = side ? p.ei2 : p.ei1;
  int e = blk * 256 + t;
  int tgt = ei[e];
  int r = atomicAdd(&p.deg8[((size_t)side * NN + tgt) * 8 + c], 1);
  p.rnk[side * EE + e] = r;
}

// scatter: deterministic position, NO atomics
__device__ __forceinline__ void scatter_one(const GArgs& p, int idx, int t){
  int side = idx >> 9, blk = idx & 511, c = idx & 7;
  const int* ei = side ? p.ei2 : p.ei1;
  const int* sb8 = p.sb8 + (size_t)side * NN * 8;
  int* srt = side ? p.srt2 : p.srt1;
  int e = blk * 256 + t;
  int tgt = ei[e], src = ei[EE + e];
  int pos = sb8[tgt * 8 + c] + p.rnk[side * EE + e];
  srt[pos] = src;
}

__device__ __forceinline__ void scan_one(const GArgs& p, int b, int t, int* part){
  const int* d8 = p.deg8 + (size_t)b * NN * 8;
  int* offs = b ? p.offs2 : p.offs1;
  int* sb8  = p.sb8 + (size_t)b * NN * 8;
  int* degt = p.degt + b * NN;
  const int base = t * 32;
  int loc[32];
  int s = 0;
  for (int i = 0; i < 32; i++){
    loc[i] = s;
    int tot = 0;
    #pragma unroll
    for (int c = 0; c < 8; c++) tot += d8[(base + i) * 8 + c];
    s += tot;
  }
  part[t] = s;
  __syncthreads();
  for (int off = 1; off < 256; off <<= 1){
    int v = (t >= off) ? part[t - off] : 0;
    __syncthreads();
    part[t] += v;
    __syncthreads();
  }
  int pre = (t == 0) ? 0 : part[t - 1];
  for (int i = 0; i < 32; i++){
    int node = base + i;
    int o = pre + loc[i];
    offs[node] = o;
    int run = o, tot = 0;
    #pragma unroll
    for (int c = 0; c < 8; c++){
      int dv = d8[node * 8 + c];
      sb8[node * 8 + c] = run;
      run += dv; tot += dv;
    }
    degt[node] = tot;
  }
  if (t == 255) offs[NN] = part[255];
}

__device__ __forceinline__ void transpose_one(const GArgs& p, int a, int t, u16* T){
  int side = a >> 7, blk = a & 127;
  const u16* src = p.xb + (size_t)side * NN * DD;
  u16* dst = p.xt + (size_t)side * DD * NN;
  const int n0 = blk * 64;
  #pragma unroll
  for (int i = 0; i < 4; i++){
    int s = i * 256 + t; int r = s >> 4, c8 = (s & 15) << 3;
    *(uint4*)&T[r * 136 + c8] = *(const uint4*)(src + (size_t)(n0 + r) * DD + c8);
  }
  __syncthreads();
  #pragma unroll
  for (int i = 0; i < 8; i++){
    int s = i * 256 + t;
    int d = s >> 4, n4 = (s & 15) << 2;
    uint32_t a0 = T[(n4 + 0) * 136 + d];
    uint32_t a1 = T[(n4 + 1) * 136 + d];
    uint32_t a2 = T[(n4 + 2) * 136 + d];
    uint32_t a3 = T[(n4 + 3) * 136 + d];
    uint2 pk; pk.x = a0 | (a1 << 16); pk.y = a2 | (a3 << 16);
    *(uint2*)(dst + (size_t)d * NN + n0 + n4) = pk;
  }
}

__device__ __forceinline__ void gather_one(const GArgs& p, int nv, int lane){
  int side = nv >> 13, node = nv & (NN - 1);
  const int* offs = side ? p.offs2 : p.offs1;
  const int* srt  = side ? p.srt2  : p.srt1;
  const u16* base = p.PQ + (size_t)side * NN * 1024;
  const int beg = offs[node], end = offs[node + 1];

  uint4 qv = *(const uint4*)(base + (size_t)node * 1024 + 512 + (lane << 3));
  float q[8];
  {
    uint32_t qw[4] = {qv.x, qv.y, qv.z, qv.w};
    #pragma unroll
    for (int i = 0; i < 4; i++){
      q[i * 2]     = bf2f((u16)(qw[i] & 0xffffu));
      q[i * 2 + 1] = bf2f((u16)(qw[i] >> 16));
    }
  }
  float acc[8] = {0.f,0.f,0.f,0.f,0.f,0.f,0.f,0.f};
  int e = beg;
  for (; e + 3 < end; e += 4){
    int sA = srt[e], sB = srt[e+1], sC = srt[e+2], sD = srt[e+3];
    uint4 pA = *(const uint4*)(base + (size_t)sA * 1024 + (lane << 3));
    uint4 pB = *(const uint4*)(base + (size_t)sB * 1024 + (lane << 3));
    uint4 pC = *(const uint4*)(base + (size_t)sC * 1024 + (lane << 3));
    uint4 pD = *(const uint4*)(base + (size_t)sD * 1024 + (lane << 3));
    uint32_t aw[4] = {pA.x, pA.y, pA.z, pA.w};
    uint32_t bw[4] = {pB.x, pB.y, pB.z, pB.w};
    uint32_t cw[4] = {pC.x, pC.y, pC.z, pC.w};
    uint32_t dw[4] = {pD.x, pD.y, pD.z, pD.w};
    #pragma unroll
    for (int i = 0; i < 4; i++){
      acc[i*2]   += fmaxf(bf2f((u16)(aw[i] & 0xffffu)) + q[i*2],   0.f)
                  + fmaxf(bf2f((u16)(bw[i] & 0xffffu)) + q[i*2],   0.f)
                  + fmaxf(bf2f((u16)(cw[i] & 0xffffu)) + q[i*2],   0.f)
                  + fmaxf(bf2f((u16)(dw[i] & 0xffffu)) + q[i*2],   0.f);
      acc[i*2+1] += fmaxf(bf2f((u16)(aw[i] >> 16))     + q[i*2+1], 0.f)
                  + fmaxf(bf2f((u16)(bw[i] >> 16))     + q[i*2+1], 0.f)
                  + fmaxf(bf2f((u16)(cw[i] >> 16))     + q[i*2+1], 0.f)
                  + fmaxf(bf2f((u16)(dw[i] >> 16))     + q[i*2+1], 0.f);
    }
  }
  for (; e < end; e++){
    int sA = srt[e];
    uint4 pA = *(const uint4*)(base + (size_t)sA * 1024 + (lane << 3));
    uint32_t aw[4] = {pA.x, pA.y, pA.z, pA.w};
    #pragma unroll
    for (int i = 0; i < 4; i++){
      acc[i*2]   += fmaxf(bf2f((u16)(aw[i] & 0xffffu)) + q[i*2],   0.f);
      acc[i*2+1] += fmaxf(bf2f((u16)(aw[i] >> 16))     + q[i*2+1], 0.f);
    }
  }
  uint4 pk;
  pk.x = (uint32_t)f2bf(acc[0]) | ((uint32_t)f2bf(acc[1]) << 16);
  pk.y = (uint32_t)f2bf(acc[2]) | ((uint32_t)f2bf(acc[3]) << 16);
  pk.z = (uint32_t)f2bf(acc[4]) | ((uint32_t)f2bf(acc[5]) << 16);
  pk.w = (uint32_t)f2bf(acc[6]) | ((uint32_t)f2bf(acc[7]) << 16);
  *(uint4*)(p.S + ((size_t)side * NN + node) * 512 + (lane << 3)) = pk;
}

// attention block (XaS + XbS LDS staging). sh >= 26112 u16.
__device__ __forceinline__ void attn_one(const GArgs& p, int a, int t, u16* sh){
  const int side = a >> 7;
  const int g = a & 63, h = (a >> 6) & 1;
  const u16* Xa = p.xb + (size_t)side * NN * DD;
  const u16* Xb = p.xb + (size_t)(1 - side) * NN * DD;
  const u16* Xt = p.xt + (size_t)(1 - side) * DD * NN;
  u16* Uside = p.U + (size_t)side * NN * 512;
  u16* XaS = sh;            // 64*136
  u16* XbS = sh + 8704;     // 128*136

  const int w = t >> 6, lane = t & 63;
  const int lr = lane & 15, lq = lane >> 4;

  {
    const u16* sa = Xa + ((size_t)g * GS + h * 64) * DD;
    #pragma unroll
    for (int i = 0; i < 4; i++){
      int s = i * 256 + t; int r = s >> 4, c8 = (s & 15) << 3;
      *(uint4*)&XaS[r * 136 + c8] = *(const uint4*)(sa + (size_t)r * DD + c8);
    }
    const u16* sb = Xb + (size_t)g * GS * DD;
    #pragma unroll
    for (int i = 0; i < 8; i++){
      int s = i * 256 + t; int r = s >> 4, c8 = (s & 15) << 3;
      *(uint4*)&XbS[r * 136 + c8] = *(const uint4*)(sb + (size_t)r * DD + c8);
    }
  }
  __syncthreads();

  f32x4 sc[8];
  #pragma unroll
  for (int ct = 0; ct < 8; ct++) sc[ct] = (f32x4){0.f, 0.f, 0.f, 0.f};
  #pragma unroll
  for (int kb = 0; kb < 4; kb++){
    bf16x8 aa = *(const bf16x8*)&XaS[(w * 16 + lr) * 136 + kb * 32 + (lq << 3)];
    #pragma unroll
    for (int ct = 0; ct < 8; ct++){
      bf16x8 bb = *(const bf16x8*)&XbS[(ct * 16 + lr) * 136 + kb * 32 + (lq << 3)];
      sc[ct] = __builtin_amdgcn_mfma_f32_16x16x32_bf16(aa, bb, sc[ct], 0, 0, 0);
    }
  }
  float inv[4];
  #pragma unroll
  for (int rr = 0; rr < 4; rr++){
    float m = sc[0][rr];
    #pragma unroll
    for (int ct = 1; ct < 8; ct++) m = fmaxf(m, sc[ct][rr]);
    #pragma unroll
    for (int sh_ = 1; sh_ < 16; sh_ <<= 1) m = fmaxf(m, __shfl_xor(m, sh_, 64));
    float s = 0.f;
    #pragma unroll
    for (int ct = 0; ct < 8; ct++){
      float e = __expf(sc[ct][rr] - m);
      sc[ct][rr] = e; s += e;
    }
    #pragma unroll
    for (int sh_ = 1; sh_ < 16; sh_ <<= 1) s += __shfl_xor(s, sh_, 64);
    inv[rr] = 1.f / s;
  }
  #pragma unroll
  for (int ct = 0; ct < 8; ct++)
    #pragma unroll
    for (int rr = 0; rr < 4; rr++)
      XaS[(w * 16 + lq * 4 + rr) * 136 + ct * 16 + lr] = f2bf(sc[ct][rr] * inv[rr]);
  __syncthreads();

  f32x4 o[8];
  #pragma unroll
  for (int ct = 0; ct < 8; ct++) o[ct] = (f32x4){0.f, 0.f, 0.f, 0.f};
  #pragma unroll
  for (int kb = 0; kb < 4; kb++){
    bf16x8 aa = *(const bf16x8*)&XaS[(w * 16 + lr) * 136 + kb * 32 + (lq << 3)];
    #pragma unroll
    for (int ct = 0; ct < 8; ct++){
      bf16x8 bb = *(const bf16x8*)(Xt + (size_t)(ct * 16 + lr) * NN + g * GS + kb * 32 + (lq << 3));
      o[ct] = __builtin_amdgcn_mfma_f32_16x16x32_bf16(aa, bb, o[ct], 0, 0, 0);
    }
  }
  const u16* XaEp = Xa + ((size_t)g * GS + h * 64) * DD;
  #pragma unroll
  for (int ct = 0; ct < 8; ct++)
    #pragma unroll
    for (int rr = 0; rr < 4; rr++){
      int row = w * 16 + lq * 4 + rr, col = ct * 16 + lr;
      float xa = bf2f(XaEp[(size_t)row * DD + col]);
      Uside[((size_t)g * GS + h * 64 + row) * 512 + 256 + col] = f2bf(xa - o[ct][rr]);
    }
}

// ================= kernels =================
__global__ __launch_bounds__(256)
void pre_k(GArgs p){
  int b = blockIdx.x, t = threadIdx.x;
  if (b < 2692) prep_weights(p, b, t);
  else if (b < 2692 + 8192) cast_x_one(p, b - 2692, t);
  else hist_one(p, b - (2692 + 8192), t);
}

__global__ __launch_bounds__(256)
void scan_k(GArgs p){
  __shared__ int part[256];
  scan_one(p, blockIdx.x, threadIdx.x, part);
}

__global__ __launch_bounds__(256)
void mid_k(GArgs p){
  __shared__ u16 sh[32768];
  int b = blockIdx.x, t = threadIdx.x;
  if (b < 1024)
    gemm_body<false,false,false,u16>(p.xb, 128, p.WtPQ, p.bPQ, nullptr, nullptr, nullptr,
                                     p.PQ, 1024, 128, b & 7, b >> 3,
                                     sh, sh + 16384, t);
  else if (b < 2048) scatter_one(p, b - 1024, t);
  else transpose_one(p, b - 2048, t, sh);
}

__global__ __launch_bounds__(256)
void gather_k(GArgs p){
  gather_one(p, blockIdx.y * NN + blockIdx.x * 4 + (threadIdx.x >> 6),
             threadIdx.x & 63);
}

__global__ __launch_bounds__(256)
void msgattn_k(GArgs p){
  __shared__ u16 sh[32768];
  int b = blockIdx.x, t = threadIdx.x;
  if (b < 256)
    gemm_body<false,true,false,u16>(p.S, 512, p.Wtm2, p.mb2, p.degt, nullptr, nullptr,
                                    p.U, 512, 512, b & 1, b >> 1,
                                    sh, sh + 16384, t);
  else
    attn_one(p, b - 256, t, sh);
}

__global__ __launch_bounds__(256)
void h1_k(GArgs p){
  __shared__ u16 sh[32768];
  gemm_body<true,false,false,u16>(p.U, 512, p.Wtu1, p.ub1, nullptr, nullptr, nullptr,
                                  p.H1, 512, 512, blockIdx.x, blockIdx.y,
                                  sh, sh + 16384, threadIdx.x);
}
__global__ __launch_bounds__(256)
void h2_k(GArgs p){
  __shared__ u16 sh[32768];
  gemm_body<true,false,false,u16>(p.H1, 512, p.Wtu2, p.ub2, nullptr, nullptr, nullptr,
                                  p.H2, 256, 512, blockIdx.x, blockIdx.y,
                                  sh, sh + 16384, threadIdx.x);
}
__global__ __launch_bounds__(256)
void out_k(GArgs p){
  __shared__ u16 sh[32768];
  gemm_body<false,false,true,float>(p.H2, 256, p.Wtu3, p.ub3, nullptr, p.x1, p.x2,
                                    p.out, 128, 256, blockIdx.x, blockIdx.y,
                                    sh, sh + 16384, threadIdx.x);
}

extern "C" void kernel_launch(void* const* d_in, const int* in_sizes, int n_in,
                              void* d_out, int out_size, void* d_ws, size_t ws_size,
                              hipStream_t stream)
{
  GArgs a;
  a.x1  = (const float*)d_in[0];
  a.ei1 = (const int*)  d_in[1];
  a.x2  = (const float*)d_in[3];
  a.ei2 = (const int*)  d_in[4];
  a.mW1 = (const float*)d_in[6];
  a.mb1 = (const float*)d_in[7];
  a.mW2 = (const float*)d_in[8];
  a.mb2 = (const float*)d_in[9];
  a.uW1 = (const float*)d_in[10];
  a.ub1 = (const float*)d_in[11];
  a.uW2 = (const float*)d_in[12];
  a.ub2 = (const float*)d_in[13];
  a.uW3 = (const float*)d_in[14];
  a.ub3 = (const float*)d_in[15];
  a.out = (float*)d_out;

  char* w = (char*)d_ws;
  auto alloc = [&](size_t b){ char* p = w; w += (b + 255) & ~(size_t)255; return p; };
  a.S    = (u16*)alloc((size_t)2 * NN * 512 * 2);
  a.PQ   = (u16*)alloc((size_t)2 * NN * 1024 * 2);
  a.xb   = (u16*)alloc((size_t)2 * NN * DD * 2);
  a.xt   = (u16*)alloc((size_t)2 * DD * NN * 2);
  a.U    = (u16*)alloc((size_t)2 * NN * 512 * 2);
  a.H1   = (u16*)alloc((size_t)2 * NN * 512 * 2);
  a.H2   = (u16*)alloc((size_t)2 * NN * 256 * 2);
  a.deg8 = (int*)alloc((size_t)2 * NN * 8 * 4);
  a.degt = (int*)alloc((size_t)2 * NN * 4);
  a.sb8  = (int*)alloc((size_t)2 * NN * 8 * 4);
  a.rnk  = (int*)alloc((size_t)2 * EE * 4);
  a.offs1 = (int*)alloc((NN + 1) * 4);
  a.offs2 = (int*)alloc((NN + 1) * 4);
  a.srt1  = (int*)alloc((size_t)EE * 4);
  a.srt2  = (int*)alloc((size_t)EE * 4);
  a.WtPQ = (u16*)alloc(1024 * 128 * 2);
  a.bPQ  = (float*)alloc(1024 * 4);
  a.Wtm2 = (u16*)alloc(256 * 512 * 2);
  a.Wtu1 = (u16*)alloc(512 * 512 * 2);
  a.Wtu2 = (u16*)alloc(256 * 512 * 2);
  a.Wtu3 = (u16*)alloc(128 * 256 * 2);

  hipMemsetAsync(a.deg8, 0, (size_t)2 * NN * 8 * 4, stream);
  pre_k<<<2692 + 8192 + 1024, 256, 0, stream>>>(a);
  scan_k<<<2, 256, 0, stream>>>(a);
  mid_k<<<2304, 256, 0, stream>>>(a);
  gather_k<<<dim3(2048, 2), 256, 0, stream>>>(a);
  msgattn_k<<<512, 256, 0, stream>>>(a);
  h1_k<<<dim3(4, 128), 256, 0, stream>>>(a);
  h2_k<<<dim3(2, 128), 256, 0, stream>>>(a);
  out_k<<<dim3(1, 128), 256, 0, stream>>>(a);
}